// Round 3
// baseline (3530.178 us; speedup 1.0000x reference)
//
#include <hip/hip_runtime.h>
#include <hip/hip_fp16.h>
#include <stdint.h>

#define Bsz 64
#define Tsz 1024
#define Dsz 256
#define UNITSn 256
#define Zdim 1024      // 4*UNITS

// lstm v3: thread (half=tid>>8, u=tid&255) computes half-K partial dots for the
// 4 gate columns {g*256+u}. Per thread 64 uint4 of f16-pair W:
//   wr[4][8]  (128 VGPRs) : k2rel 0..31  per gate
//   streamed  (32 uint4)  : k2rel 32..63 per gate, from L2 each step (256KB/WG)
// Forced 256-VGPR budget via amdgpu_waves_per_eu(2,2).

typedef _Float16 half2v __attribute__((ext_vector_type(2)));

__device__ __forceinline__ float dot2acc(uint32_t w, uint32_t h, float acc) {
#if __has_builtin(__builtin_amdgcn_fdot2)
  return __builtin_amdgcn_fdot2(__builtin_bit_cast(half2v, w),
                                __builtin_bit_cast(half2v, h), acc, false);
#else
  __half2 wv = __builtin_bit_cast(__half2, w);
  __half2 hv = __builtin_bit_cast(__half2, h);
  acc = fmaf(__half2float(__low2half(wv)),  __half2float(__low2half(hv)),  acc);
  acc = fmaf(__half2float(__high2half(wv)), __half2float(__high2half(hv)), acc);
  return acc;
#endif
}

__device__ __forceinline__ float dot4(const uint4& w, const uint4& h, float acc) {
  acc = dot2acc(w.x, h.x, acc); acc = dot2acc(w.y, h.y, acc);
  acc = dot2acc(w.z, h.z, acc); acc = dot2acc(w.w, h.w, acc);
  return acc;
}

__device__ __forceinline__ float sigm(float x)   { return 1.0f / (1.0f + __expf(-x)); }
__device__ __forceinline__ float tanh_f(float x) { return 1.0f - 2.0f / (__expf(2.0f * x) + 1.0f); }

// Repack W[256][1024] fp32 -> f16-pair layouts:
//  Wreg[(g*8+j)*512 + t]          : k2 = (t>>8)*64 + j*4 + e,       col = g*256+(t&255)
//  Wg[((jj8*512 + t)*4 + g)]      : k2 = (t>>8)*64 + 32 + jj8*4 + e, col = g*256+(t&255)
__global__ __launch_bounds__(256) void convert_w3(const float* __restrict__ W,
                                                  uint4* __restrict__ Wreg,
                                                  uint4* __restrict__ Wg) {
  int i = blockIdx.x * 256 + threadIdx.x;    // 32768 total uint4
  if (i >= 32768) return;
  bool isReg = i < 16384;
  int t, g, k2rel, outIdx;
  if (isReg) {
    int q = i >> 9; t = i & 511;
    g = q >> 3; k2rel = (q & 7) * 4;
    outIdx = i;
  } else {
    int i2 = i - 16384;
    g = i2 & 3; t = (i2 >> 2) & 511; int jj8 = i2 >> 11;
    k2rel = 32 + jj8 * 4;
    outIdx = i2;
  }
  int col = g * 256 + (t & 255);
  int kbase = (t >> 8) * 64 + k2rel;
  uint32_t d[4];
#pragma unroll
  for (int e = 0; e < 4; e++) {
    int k2 = kbase + e;
    float w0 = W[(size_t)(2 * k2) * Zdim + col];
    float w1 = W[(size_t)(2 * k2 + 1) * Zdim + col];
    __half2 p = __floats2half2_rn(w0, w1);
    d[e] = __builtin_bit_cast(uint32_t, p);
  }
  uint4 v = make_uint4(d[0], d[1], d[2], d[3]);
  if (isReg) Wreg[outIdx] = v;
  else       Wg[outIdx] = v;
}

// xz[(tloc*64 + b)*1024 + n] = x[b][t0+tloc][:] @ U[:,n] + bias[n]   (fp32 GEMM)
__global__ __launch_bounds__(256) void proj_gemm(
    const float* __restrict__ x, const float* __restrict__ U,
    const float* __restrict__ bias, float* __restrict__ xz, int t0) {
  __shared__ float At[32][68];
  __shared__ float Bt[32][68];
  const int tid  = threadIdx.x;
  const int n0   = blockIdx.x * 64;
  const int tloc = blockIdx.y;
  const int t    = t0 + tloc;
  const int tm = tid >> 4, tn = tid & 15;
  const int am = tid >> 3, ak = (tid & 7) * 4;
  const int bk = tid >> 4, bn = (tid & 15) * 4;
  const float* xb = x + (size_t)t * Dsz;

  float acc[4][4] = {};
  for (int k0 = 0; k0 < Dsz; k0 += 32) {
    float4 a0 = *(const float4*)(xb + (size_t)am * (Tsz * Dsz) + k0 + ak);
    float4 a1 = *(const float4*)(xb + (size_t)(am + 32) * (Tsz * Dsz) + k0 + ak);
    float4 b0 = *(const float4*)(U + (size_t)(k0 + bk) * Zdim + n0 + bn);
    float4 b1 = *(const float4*)(U + (size_t)(k0 + bk + 16) * Zdim + n0 + bn);
    __syncthreads();
    At[ak + 0][am] = a0.x; At[ak + 1][am] = a0.y; At[ak + 2][am] = a0.z; At[ak + 3][am] = a0.w;
    At[ak + 0][am + 32] = a1.x; At[ak + 1][am + 32] = a1.y; At[ak + 2][am + 32] = a1.z; At[ak + 3][am + 32] = a1.w;
    *(float4*)&Bt[bk][bn]      = b0;
    *(float4*)&Bt[bk + 16][bn] = b1;
    __syncthreads();
#pragma unroll
    for (int kk = 0; kk < 32; kk++) {
      float4 av = *(const float4*)&At[kk][tm * 4];
      float4 bv = *(const float4*)&Bt[kk][tn * 4];
      float a_[4] = {av.x, av.y, av.z, av.w};
      float b_[4] = {bv.x, bv.y, bv.z, bv.w};
#pragma unroll
      for (int i = 0; i < 4; i++)
#pragma unroll
        for (int j = 0; j < 4; j++) acc[i][j] = fmaf(a_[i], b_[j], acc[i][j]);
    }
  }
  float4 bb = *(const float4*)&bias[n0 + tn * 4];
  float bias_[4] = {bb.x, bb.y, bb.z, bb.w};
#pragma unroll
  for (int i = 0; i < 4; i++) {
    float4 o;
    o.x = acc[i][0] + bias_[0]; o.y = acc[i][1] + bias_[1];
    o.z = acc[i][2] + bias_[2]; o.w = acc[i][3] + bias_[3];
    *(float4*)(xz + ((size_t)tloc * 64 + tm * 4 + i) * Zdim + n0 + tn * 4) = o;
  }
}

// One WG (512 thr = 8 waves) per batch, 1 WG/CU, 2 waves/SIMD, 256-VGPR budget.
__global__ __launch_bounds__(512)
__attribute__((amdgpu_waves_per_eu(2, 2)))
void lstm_chunk(const float* __restrict__ xz, const uint4* __restrict__ Wreg,
                const uint4* __restrict__ Wg, float* __restrict__ out,
                uint4* __restrict__ h_state, float* __restrict__ c_state,
                int t0, int Tc, int n_out) {
  __shared__ uint4 hq4[2][32];      // packed f16 h, double-buffered (1 KB)
  __shared__ float4 ppL[256];       // half=1 partial sums (4 KB)
  const int tid  = threadIdx.x;
  const int b    = blockIdx.x;
  const int half = tid >> 8, u = tid & 255;

  uint4 wr[4][8];
#pragma unroll
  for (int g = 0; g < 4; g++)
#pragma unroll
    for (int j = 0; j < 8; j++)
      wr[g][j] = Wreg[(size_t)(g * 8 + j) * 512 + tid];

  float c = 0.0f;
  if (t0 == 0) {
    if (tid < 64) ((uint4*)hq4)[tid] = make_uint4(0, 0, 0, 0);
  } else {
    if (tid < 32)  ((uint4*)hq4)[tid] = h_state[(size_t)b * 32 + tid];
    if (half == 0) c = c_state[(size_t)b * 256 + u];
  }
  __syncthreads();

  const float* xzb = xz + (size_t)b * Zdim + u;
  float nx0 = 0, nx1 = 0, nx2 = 0, nx3 = 0;
  if (half == 0) { nx0 = xzb[0]; nx1 = xzb[256]; nx2 = xzb[512]; nx3 = xzb[768]; }
  const uint4* wgt = Wg + (size_t)tid * 4;   // batch k at wgt + k*2048, 4 uint4 (g=0..3)

  for (int tl = 0; tl < Tc; tl++) {
    const int buf = tl & 1;
    const uint4* hb = hq4[buf] + half * 16;
    float a0 = 0, a1 = 0, a2 = 0, a3 = 0;

    // issue stream batches 0..3 (64 regs in flight max)
    uint4 sa[4][4];
#pragma unroll
    for (int k = 0; k < 4; k++) {
      const uint4* p = wgt + (size_t)k * 2048;
#pragma unroll
      for (int g = 0; g < 4; g++) sa[k][g] = p[g];
    }
    // phase A: VGPR-resident W (128 dot2/thread) — covers L2 latency of sa
#pragma unroll
    for (int j = 0; j < 8; j++) {
      uint4 h4 = hb[j];
      a0 = dot4(wr[0][j], h4, a0);
      a1 = dot4(wr[1][j], h4, a1);
      a2 = dot4(wr[2][j], h4, a2);
      a3 = dot4(wr[3][j], h4, a3);
    }
    // phase B: consume sa[k], issue sb[k] (batches 4..7), then consume sb
    uint4 sb[4][4];
#pragma unroll
    for (int k = 0; k < 4; k++) {
      const uint4* p = wgt + (size_t)(k + 4) * 2048;
#pragma unroll
      for (int g = 0; g < 4; g++) sb[k][g] = p[g];
      uint4 h4 = hb[8 + k];
      a0 = dot4(sa[k][0], h4, a0);
      a1 = dot4(sa[k][1], h4, a1);
      a2 = dot4(sa[k][2], h4, a2);
      a3 = dot4(sa[k][3], h4, a3);
    }
#pragma unroll
    for (int k = 0; k < 4; k++) {
      uint4 h4 = hb[12 + k];
      a0 = dot4(sb[k][0], h4, a0);
      a1 = dot4(sb[k][1], h4, a1);
      a2 = dot4(sb[k][2], h4, a2);
      a3 = dot4(sb[k][3], h4, a3);
    }

    if (half) ppL[u] = make_float4(a0, a1, a2, a3);
    __syncthreads();
    if (!half) {
      float4 pp = ppL[u];
      float z0 = a0 + pp.x + nx0, z1 = a1 + pp.y + nx1;
      float z2 = a2 + pp.z + nx2, z3 = a3 + pp.w + nx3;
      if (tl + 1 < Tc) {
        const float* xn = xzb + (size_t)(tl + 1) * (Bsz * Zdim);
        nx0 = xn[0]; nx1 = xn[256]; nx2 = xn[512]; nx3 = xn[768];
      }
      float ig = sigm(z0), fg = sigm(z1), gg = tanh_f(z2), og = sigm(z3);
      c = fg * c + ig * gg;
      float hn = og * tanh_f(c);
      int ot = (t0 + tl) - (Tsz - n_out);
      if (ot >= 0) out[((size_t)b * n_out + ot) * UNITSn + u] = hn;
      ((__half*)hq4[buf ^ 1])[u] = __float2half(hn);
    }
    __syncthreads();
  }
  if (tid < 32)  h_state[(size_t)b * 32 + tid] = ((uint4*)hq4)[(Tc & 1) * 32 + tid];
  if (half == 0) c_state[(size_t)b * 256 + u] = c;
}

extern "C" void kernel_launch(void* const* d_in, const int* in_sizes, int n_in,
                              void* d_out, int out_size, void* d_ws, size_t ws_size,
                              hipStream_t stream) {
  const float* x    = (const float*)d_in[0];
  const float* U    = (const float*)d_in[1];
  const float* W    = (const float*)d_in[2];
  const float* bias = (const float*)d_in[3];
  float* out = (float*)d_out;
  const int n_out = out_size / (Bsz * UNITSn);   // 32

  uint8_t* ws = (uint8_t*)d_ws;
  uint4* Wreg    = (uint4*)ws;                     // 256 KB (16384 uint4)
  uint4* Wg      = (uint4*)(ws + (256u << 10));    // 256 KB
  uint4* h_state = (uint4*)(ws + (512u << 10));    // 32 KB
  float* c_state = (float*)(ws + (544u << 10));    // 64 KB
  float* xz      = (float*)(ws + (1u << 20));      // Tc*64*1024 fp32

  int Tc = Tsz;
  while (Tc > 1 && (size_t)(1u << 20) + (size_t)Tc * (Bsz * Zdim) * 4 > ws_size) Tc >>= 1;

  convert_w3<<<dim3(128), dim3(256), 0, stream>>>(W, Wreg, Wg);

  for (int t0 = 0; t0 < Tsz; t0 += Tc) {
    proj_gemm<<<dim3(16, Tc), dim3(256), 0, stream>>>(x, U, bias, xz, t0);
    lstm_chunk<<<dim3(Bsz), dim3(512), 0, stream>>>(xz, Wreg, Wg, out, h_state,
                                                    c_state, t0, Tc, n_out);
  }
}

// Round 4
// 2081.898 us; speedup vs baseline: 1.6957x; 1.6957x over previous
//
#include <hip/hip_runtime.h>
#include <hip/hip_fp16.h>
#include <stdint.h>

#define Bsz 64
#define Tsz 1024
#define Dsz 256
#define UNITSn 256
#define Zdim 1024      // 4*UNITS
#define NWV 6          // uint4 per gate-column in VGPRs  (k2rel 0..23)
#define NWL 2          // uint4 per gate-column in LDS    (k2rel 24..31)

// lstm v4: 1024-thread WG per batch. Thread (q=tid>>8, u=tid&255) computes
// quarter-K (64 k-elems = 32 k2) partial dots for the 4 gate columns {g*256+u}.
// Per-thread W = 32 uint4 of f16-pairs: 24 in VGPRs (96 regs, fits the 128-reg
// budget at 4 waves/EU), 8 in LDS (128 KB). All of W is CU-resident.

typedef _Float16 half2v __attribute__((ext_vector_type(2)));

__device__ __forceinline__ float dot2acc(uint32_t w, uint32_t h, float acc) {
#if __has_builtin(__builtin_amdgcn_fdot2)
  return __builtin_amdgcn_fdot2(__builtin_bit_cast(half2v, w),
                                __builtin_bit_cast(half2v, h), acc, false);
#else
  __half2 wv = __builtin_bit_cast(__half2, w);
  __half2 hv = __builtin_bit_cast(__half2, h);
  acc = fmaf(__half2float(__low2half(wv)),  __half2float(__low2half(hv)),  acc);
  acc = fmaf(__half2float(__high2half(wv)), __half2float(__high2half(hv)), acc);
  return acc;
#endif
}

__device__ __forceinline__ float dot4(const uint4& w, const uint4& h, float acc) {
  acc = dot2acc(w.x, h.x, acc); acc = dot2acc(w.y, h.y, acc);
  acc = dot2acc(w.z, h.z, acc); acc = dot2acc(w.w, h.w, acc);
  return acc;
}

__device__ __forceinline__ float sigm(float x)   { return 1.0f / (1.0f + __expf(-x)); }
__device__ __forceinline__ float tanh_f(float x) { return 1.0f - 2.0f / (__expf(2.0f * x) + 1.0f); }

// Repack W[256][1024] fp32 -> f16-pair layouts for lstm v4 (t = 0..1023):
//  WregBuf[(g*NWV+j)*1024 + t]: k2 = (t>>8)*32 + j*4 + e,          col = g*256+(t&255)
//  WldsBuf[(g*NWL+jj)*1024 + t]: k2 = (t>>8)*32 + NWV*4 + jj*4 + e, col = g*256+(t&255)
__global__ __launch_bounds__(256) void convert_w4(const float* __restrict__ W,
                                                  uint4* __restrict__ WregBuf,
                                                  uint4* __restrict__ WldsBuf) {
  int i = blockIdx.x * 256 + threadIdx.x;    // 32768 uint4 total
  if (i >= 32768) return;
  bool isReg = i < NWV * 4 * 1024;           // 24576
  int t, g, k2rel, outIdx;
  if (isReg) {
    int cI = i >> 10; t = i & 1023;
    g = cI / NWV; int j = cI - g * NWV;
    k2rel = j * 4;
    outIdx = i;
  } else {
    int i2 = i - NWV * 4 * 1024;
    int cI = i2 >> 10; t = i2 & 1023;
    g = cI >> 1; int jj = cI & 1;
    k2rel = NWV * 4 + jj * 4;
    outIdx = i2;
  }
  int col = g * 256 + (t & 255);
  int kbase = (t >> 8) * 32 + k2rel;
  uint32_t d[4];
#pragma unroll
  for (int e = 0; e < 4; e++) {
    int k2 = kbase + e;
    float w0 = W[(size_t)(2 * k2) * Zdim + col];
    float w1 = W[(size_t)(2 * k2 + 1) * Zdim + col];
    __half2 p = __floats2half2_rn(w0, w1);
    d[e] = __builtin_bit_cast(uint32_t, p);
  }
  uint4 v = make_uint4(d[0], d[1], d[2], d[3]);
  if (isReg) WregBuf[outIdx] = v;
  else       WldsBuf[outIdx] = v;
}

// xz[(tloc*64 + b)*1024 + n] = x[b][t0+tloc][:] @ U[:,n] + bias[n]   (fp32 GEMM)
__global__ __launch_bounds__(256) void proj_gemm(
    const float* __restrict__ x, const float* __restrict__ U,
    const float* __restrict__ bias, float* __restrict__ xz, int t0) {
  __shared__ float At[32][68];
  __shared__ float Bt[32][68];
  const int tid  = threadIdx.x;
  const int n0   = blockIdx.x * 64;
  const int tloc = blockIdx.y;
  const int t    = t0 + tloc;
  const int tm = tid >> 4, tn = tid & 15;
  const int am = tid >> 3, ak = (tid & 7) * 4;
  const int bk = tid >> 4, bn = (tid & 15) * 4;
  const float* xb = x + (size_t)t * Dsz;

  float acc[4][4] = {};
  for (int k0 = 0; k0 < Dsz; k0 += 32) {
    float4 a0 = *(const float4*)(xb + (size_t)am * (Tsz * Dsz) + k0 + ak);
    float4 a1 = *(const float4*)(xb + (size_t)(am + 32) * (Tsz * Dsz) + k0 + ak);
    float4 b0 = *(const float4*)(U + (size_t)(k0 + bk) * Zdim + n0 + bn);
    float4 b1 = *(const float4*)(U + (size_t)(k0 + bk + 16) * Zdim + n0 + bn);
    __syncthreads();
    At[ak + 0][am] = a0.x; At[ak + 1][am] = a0.y; At[ak + 2][am] = a0.z; At[ak + 3][am] = a0.w;
    At[ak + 0][am + 32] = a1.x; At[ak + 1][am + 32] = a1.y; At[ak + 2][am + 32] = a1.z; At[ak + 3][am + 32] = a1.w;
    *(float4*)&Bt[bk][bn]      = b0;
    *(float4*)&Bt[bk + 16][bn] = b1;
    __syncthreads();
#pragma unroll
    for (int kk = 0; kk < 32; kk++) {
      float4 av = *(const float4*)&At[kk][tm * 4];
      float4 bv = *(const float4*)&Bt[kk][tn * 4];
      float a_[4] = {av.x, av.y, av.z, av.w};
      float b_[4] = {bv.x, bv.y, bv.z, bv.w};
#pragma unroll
      for (int i = 0; i < 4; i++)
#pragma unroll
        for (int j = 0; j < 4; j++) acc[i][j] = fmaf(a_[i], b_[j], acc[i][j]);
    }
  }
  float4 bb = *(const float4*)&bias[n0 + tn * 4];
  float bias_[4] = {bb.x, bb.y, bb.z, bb.w};
#pragma unroll
  for (int i = 0; i < 4; i++) {
    float4 o;
    o.x = acc[i][0] + bias_[0]; o.y = acc[i][1] + bias_[1];
    o.z = acc[i][2] + bias_[2]; o.w = acc[i][3] + bias_[3];
    *(float4*)(xz + ((size_t)tloc * 64 + tm * 4 + i) * Zdim + n0 + tn * 4) = o;
  }
}

// One WG (1024 thr = 16 waves) per batch; 4 waves/SIMD; W fully resident.
__global__ __launch_bounds__(1024) void lstm_chunk(
    const float* __restrict__ xz, const uint4* __restrict__ WregBuf,
    const uint4* __restrict__ WldsBuf, float* __restrict__ out,
    uint4* __restrict__ h_state, float* __restrict__ c_state,
    int t0, int Tc, int n_out) {
  extern __shared__ uint4 smem4[];
  uint4* Wl   = smem4;                         // [8][1024] uint4 = 128 KB
  uint4* hq   = smem4 + 8192;                  // [2][32]  uint4 = 1 KB
  float4* pp  = (float4*)(smem4 + 8192 + 64);  // [3][256] float4 = 12 KB

  const int tid = threadIdx.x;
  const int b   = blockIdx.x;
  const int q   = tid >> 8, u = tid & 255;

  uint4 wr[4][NWV];
#pragma unroll
  for (int g = 0; g < 4; g++)
#pragma unroll
    for (int j = 0; j < NWV; j++)
      wr[g][j] = WregBuf[(size_t)(g * NWV + j) * 1024 + tid];
#pragma unroll
  for (int cc = 0; cc < 4 * NWL; cc++)
    Wl[(size_t)cc * 1024 + tid] = WldsBuf[(size_t)cc * 1024 + tid];

  float c = 0.0f;
  if (t0 == 0) {
    if (tid < 64) hq[tid] = make_uint4(0, 0, 0, 0);
  } else {
    if (tid < 32) hq[tid] = h_state[(size_t)b * 32 + tid];
    if (q == 0)   c = c_state[(size_t)b * 256 + u];
  }
  __syncthreads();

  const float* xzb = xz + (size_t)b * Zdim + u;
  float nx0 = 0, nx1 = 0, nx2 = 0, nx3 = 0;
  if (q == 0) { nx0 = xzb[0]; nx1 = xzb[256]; nx2 = xzb[512]; nx3 = xzb[768]; }

  for (int tl = 0; tl < Tc; tl++) {
    const int buf = tl & 1;
    const uint4* hb = hq + buf * 32 + q * 8;
    float a0 = 0, a1 = 0, a2 = 0, a3 = 0;
#pragma unroll
    for (int cj = 0; cj < NWL; cj++) {   // LDS-W first: loads in flight early
      uint4 h4 = hb[NWV + cj];
      uint4 w0 = Wl[(size_t)(0 * NWL + cj) * 1024 + tid];
      uint4 w1 = Wl[(size_t)(1 * NWL + cj) * 1024 + tid];
      uint4 w2 = Wl[(size_t)(2 * NWL + cj) * 1024 + tid];
      uint4 w3 = Wl[(size_t)(3 * NWL + cj) * 1024 + tid];
      a0 = dot4(w0, h4, a0); a1 = dot4(w1, h4, a1);
      a2 = dot4(w2, h4, a2); a3 = dot4(w3, h4, a3);
    }
#pragma unroll
    for (int j = 0; j < NWV; j++) {
      uint4 h4 = hb[j];
      a0 = dot4(wr[0][j], h4, a0);
      a1 = dot4(wr[1][j], h4, a1);
      a2 = dot4(wr[2][j], h4, a2);
      a3 = dot4(wr[3][j], h4, a3);
    }
    if (q) pp[(size_t)(q - 1) * 256 + u] = make_float4(a0, a1, a2, a3);
    __syncthreads();
    if (!q) {
      float4 p0 = pp[u], p1 = pp[256 + u], p2 = pp[512 + u];
      float z0 = a0 + p0.x + p1.x + p2.x + nx0;
      float z1 = a1 + p0.y + p1.y + p2.y + nx1;
      float z2 = a2 + p0.z + p1.z + p2.z + nx2;
      float z3 = a3 + p0.w + p1.w + p2.w + nx3;
      if (tl + 1 < Tc) {
        const float* xn = xzb + (size_t)(tl + 1) * (Bsz * Zdim);
        nx0 = xn[0]; nx1 = xn[256]; nx2 = xn[512]; nx3 = xn[768];
      }
      float ig = sigm(z0), fg = sigm(z1), gg = tanh_f(z2), og = sigm(z3);
      c = fg * c + ig * gg;
      float hn = og * tanh_f(c);
      int ot = (t0 + tl) - (Tsz - n_out);
      if (ot >= 0) out[((size_t)b * n_out + ot) * UNITSn + u] = hn;
      ((__half*)(hq + (buf ^ 1) * 32))[u] = __float2half(hn);
    }
    __syncthreads();
  }
  if (tid < 32) h_state[(size_t)b * 32 + tid] = hq[(Tc & 1) * 32 + tid];
  if (q == 0)   c_state[(size_t)b * 256 + u] = c;
}

extern "C" void kernel_launch(void* const* d_in, const int* in_sizes, int n_in,
                              void* d_out, int out_size, void* d_ws, size_t ws_size,
                              hipStream_t stream) {
  const float* x    = (const float*)d_in[0];
  const float* U    = (const float*)d_in[1];
  const float* W    = (const float*)d_in[2];
  const float* bias = (const float*)d_in[3];
  float* out = (float*)d_out;
  const int n_out = out_size / (Bsz * UNITSn);   // 32

  uint8_t* ws = (uint8_t*)d_ws;
  uint4* WregBuf = (uint4*)ws;                     // 384 KB (24576 uint4)
  uint4* WldsBuf = (uint4*)(ws + (384u << 10));    // 128 KB (8192 uint4)
  uint4* h_state = (uint4*)(ws + (512u << 10));    // 32 KB
  float* c_state = (float*)(ws + (544u << 10));    // 64 KB
  float* xz      = (float*)(ws + (1u << 20));      // Tc*64*1024 fp32

  int Tc = Tsz;
  while (Tc > 1 && (size_t)(1u << 20) + (size_t)Tc * (Bsz * Zdim) * 4 > ws_size) Tc >>= 1;

  convert_w4<<<dim3(128), dim3(256), 0, stream>>>(W, WregBuf, WldsBuf);

  const int ldsBytes = (8192 + 64 + 768) * 16;     // 144384 B
  hipFuncSetAttribute((const void*)lstm_chunk,
                      hipFuncAttributeMaxDynamicSharedMemorySize, ldsBytes);

  for (int t0 = 0; t0 < Tsz; t0 += Tc) {
    proj_gemm<<<dim3(16, Tc), dim3(256), 0, stream>>>(x, U, bias, xz, t0);
    lstm_chunk<<<dim3(Bsz), dim3(1024), ldsBytes, stream>>>(xz, WregBuf, WldsBuf,
                                                            out, h_state, c_state,
                                                            t0, Tc, n_out);
  }
}

// Round 5
// 1812.533 us; speedup vs baseline: 1.9476x; 1.1486x over previous
//
#include <hip/hip_runtime.h>
#include <hip/hip_fp16.h>
#include <stdint.h>

#define Bsz 64
#define Tsz 1024
#define Dsz 256
#define UNITSn 256
#define Zdim 1024      // 4*UNITS

typedef _Float16 half2v __attribute__((ext_vector_type(2)));
typedef _Float16 f16x8  __attribute__((ext_vector_type(8)));
typedef float    f32x4  __attribute__((ext_vector_type(4)));

__device__ __forceinline__ float dot2acc(uint32_t w, uint32_t h, float acc) {
#if __has_builtin(__builtin_amdgcn_fdot2)
  return __builtin_amdgcn_fdot2(__builtin_bit_cast(half2v, w),
                                __builtin_bit_cast(half2v, h), acc, false);
#else
  __half2 wv = __builtin_bit_cast(__half2, w);
  __half2 hv = __builtin_bit_cast(__half2, h);
  acc = fmaf(__half2float(__low2half(wv)),  __half2float(__low2half(hv)),  acc);
  acc = fmaf(__half2float(__high2half(wv)), __half2float(__high2half(hv)), acc);
  return acc;
#endif
}

__device__ __forceinline__ float dot4(const uint4& w, const uint4& h, float acc) {
  acc = dot2acc(w.x, h.x, acc); acc = dot2acc(w.y, h.y, acc);
  acc = dot2acc(w.z, h.z, acc); acc = dot2acc(w.w, h.w, acc);
  return acc;
}

__device__ __forceinline__ float sigm(float x)   { return 1.0f / (1.0f + __expf(-x)); }
__device__ __forceinline__ float tanh_f(float x) { return 1.0f - 2.0f / (__expf(2.0f * x) + 1.0f); }

// U[256][1024] fp32 -> UT[1024][256] f16 (transposed, k-contiguous)
__global__ __launch_bounds__(256) void convert_u(const float* __restrict__ U,
                                                 _Float16* __restrict__ UT) {
  int i = blockIdx.x * 256 + threadIdx.x;   // 262144
  int n = i >> 8, k = i & 255;
  UT[i] = (_Float16)U[(size_t)k * Zdim + n];
}

// W[256][1024] fp32 -> f16-pair layouts for lstm v5.
// Thread t (half=t>>8,u=t&255), gate g: col=g*256+u, k2 = (t>>8)*64 + k2rel + e.
//  Wop [j*512+t],  j=jj*4+g, jj=0..3 : k2rel = jj*4        (VGPR, opaque)
//  Wlds[cl*512+t], cl=jj2*4+g,jj2=0..2: k2rel = 16 + jj2*4 (LDS)
//  Wstr[kb*2048 + t*4 + g], kb=0..8  : k2rel = 28 + kb*4   (L2 stream)
__global__ __launch_bounds__(256) void convert_w5(const float* __restrict__ W,
                                                  uint4* __restrict__ Wop,
                                                  uint4* __restrict__ Wlds,
                                                  uint4* __restrict__ Wstr) {
  int i = blockIdx.x * 256 + threadIdx.x;   // 32768 uint4
  if (i >= 32768) return;
  int t, g, k2base, outIdx;
  uint4* dst;
  if (i < 8192) {
    int j = i >> 9; t = i & 511; g = j & 3; k2base = (j >> 2) * 4;
    dst = Wop; outIdx = i;
  } else if (i < 14336) {
    int i2 = i - 8192; int cl = i2 >> 9; t = i2 & 511; g = cl & 3;
    k2base = 16 + (cl >> 2) * 4; dst = Wlds; outIdx = i2;
  } else {
    int i3 = i - 14336; int kb = i3 >> 11; int r = i3 & 2047;
    t = r >> 2; g = r & 3; k2base = 28 + kb * 4; dst = Wstr; outIdx = i3;
  }
  int col = g * 256 + (t & 255);
  int kbase = (t >> 8) * 64 + k2base;
  uint32_t d[4];
#pragma unroll
  for (int e = 0; e < 4; e++) {
    int k2 = kbase + e;
    float w0 = W[(size_t)(2 * k2) * Zdim + col];
    float w1 = W[(size_t)(2 * k2 + 1) * Zdim + col];
    __half2 p = __floats2half2_rn(w0, w1);
    d[e] = __builtin_bit_cast(uint32_t, p);
  }
  dst[outIdx] = make_uint4(d[0], d[1], d[2], d[3]);
}

// xz[(tloc*64+b)*1024+n] = x[b][t][:] @ U[:,n] + bias[n] via f16 MFMA.
// Grid (4, Tc); WG 256 thr = 4 waves; tile M=64(batch) x N=256; K=256 in 8 steps.
// Wave w: n-range w*64..+63; acc[mi][ni] = frag rows 16mi.., cols ni*16..
__global__ __launch_bounds__(256) void proj_mfma(
    const float* __restrict__ x, const _Float16* __restrict__ UT,
    const float* __restrict__ bias, float* __restrict__ xz, int t0) {
  __shared__ _Float16 Ax[64][40];    // [batch][k] padded (80B rows: 2-way banks)
  __shared__ _Float16 Ux[256][40];   // [n-rel][k] padded
  const int tid  = threadIdx.x;
  const int w    = tid >> 6, lane = tid & 63;
  const int lr   = lane & 15, kg = lane >> 4;
  const int n0   = blockIdx.x * 256;
  const int tloc = blockIdx.y;
  const int t    = t0 + tloc;
  const int arow = tid >> 2, ak = (tid & 3) * 8;

  f32x4 acc[4][4];
#pragma unroll
  for (int mi = 0; mi < 4; mi++)
#pragma unroll
    for (int ni = 0; ni < 4; ni++) acc[mi][ni] = f32x4{0.f, 0.f, 0.f, 0.f};

  for (int k0 = 0; k0 < Dsz; k0 += 32) {
    const float* xp = x + ((size_t)arow * Tsz + t) * Dsz + k0 + ak;
    float4 p0 = *(const float4*)xp;
    float4 p1 = *(const float4*)(xp + 4);
    const _Float16* up = UT + (size_t)(n0 + tid) * Dsz + k0;
    f16x8 u0 = *(const f16x8*)up;
    f16x8 u1 = *(const f16x8*)(up + 8);
    f16x8 u2 = *(const f16x8*)(up + 16);
    f16x8 u3 = *(const f16x8*)(up + 24);
    __syncthreads();
    f16x8 a8;
    a8[0] = (_Float16)p0.x; a8[1] = (_Float16)p0.y;
    a8[2] = (_Float16)p0.z; a8[3] = (_Float16)p0.w;
    a8[4] = (_Float16)p1.x; a8[5] = (_Float16)p1.y;
    a8[6] = (_Float16)p1.z; a8[7] = (_Float16)p1.w;
    *(f16x8*)&Ax[arow][ak] = a8;
    *(f16x8*)&Ux[tid][0]  = u0;
    *(f16x8*)&Ux[tid][8]  = u1;
    *(f16x8*)&Ux[tid][16] = u2;
    *(f16x8*)&Ux[tid][24] = u3;
    __syncthreads();
    f16x8 af[4], uf[4];
#pragma unroll
    for (int mi = 0; mi < 4; mi++) af[mi] = *(const f16x8*)&Ax[mi * 16 + lr][kg * 8];
#pragma unroll
    for (int ni = 0; ni < 4; ni++) uf[ni] = *(const f16x8*)&Ux[w * 64 + ni * 16 + lr][kg * 8];
#pragma unroll
    for (int mi = 0; mi < 4; mi++)
#pragma unroll
      for (int ni = 0; ni < 4; ni++)
        acc[mi][ni] = __builtin_amdgcn_mfma_f32_16x16x32_f16(af[mi], uf[ni],
                                                             acc[mi][ni], 0, 0, 0);
  }
#pragma unroll
  for (int ni = 0; ni < 4; ni++) {
    int col = n0 + w * 64 + ni * 16 + lr;
    float bs = bias[col];
#pragma unroll
    for (int mi = 0; mi < 4; mi++) {
      f32x4 v = acc[mi][ni];
#pragma unroll
      for (int r = 0; r < 4; r++) {
        int brow = mi * 16 + kg * 4 + r;
        xz[((size_t)tloc * 64 + brow) * Zdim + col] = v[r] + bs;
      }
    }
  }
}

// One WG (512 thr) per batch. Thread (half=tid>>8, u=tid&255): half-K partials
// for gate cols {g*256+u}. W/thread = 64 uint4: 16 opaque-VGPR + 12 LDS + 36 L2.
__global__ __launch_bounds__(512) void lstm_chunk(
    const float* __restrict__ xz, const uint4* __restrict__ Wop,
    const uint4* __restrict__ WldsBuf, const uint4* __restrict__ Wstr,
    float* __restrict__ out, uint4* __restrict__ h_state,
    float* __restrict__ c_state, int t0, int Tc, int n_out) {
  extern __shared__ uint4 smem4[];
  uint4*  Wl = smem4;                           // 12*512 uint4 = 96 KB
  uint4*  hq = smem4 + 6144;                    // [2][32] uint4 = 1 KB
  float4* pp = (float4*)(smem4 + 6144 + 64);    // 256 float4 = 4 KB

  const int tid  = threadIdx.x;
  const int b    = blockIdx.x;
  const int half = tid >> 8, u = tid & 255;

  uint4 wop[16];
#pragma unroll
  for (int j = 0; j < 16; j++) wop[j] = Wop[(size_t)j * 512 + tid];
#pragma unroll
  for (int j = 0; j < 16; j++)
    asm volatile("" : "+v"(wop[j].x), "+v"(wop[j].y), "+v"(wop[j].z), "+v"(wop[j].w));
#pragma unroll
  for (int cl = 0; cl < 12; cl++)
    Wl[(size_t)cl * 512 + tid] = WldsBuf[(size_t)cl * 512 + tid];

  float c = 0.0f;
  if (t0 == 0) {
    if (tid < 64) hq[tid] = make_uint4(0, 0, 0, 0);
  } else {
    if (tid < 32) hq[tid] = h_state[(size_t)b * 32 + tid];
    if (half == 0) c = c_state[(size_t)b * 256 + u];
  }
  __syncthreads();

  const float* xzb = xz + (size_t)b * Zdim + u;
  float nx0 = 0, nx1 = 0, nx2 = 0, nx3 = 0;
  if (half == 0) { nx0 = xzb[0]; nx1 = xzb[256]; nx2 = xzb[512]; nx3 = xzb[768]; }
  const uint4* wstr = Wstr + (size_t)tid * 4;

#define LDB(s, kb) { const uint4* p_ = wstr + (size_t)(kb) * 2048; \
    s[0] = p_[0]; s[1] = p_[1]; s[2] = p_[2]; s[3] = p_[3]; }
#define USEB(s, hi) { uint4 h4_ = hb[hi]; \
    a0 = dot4(s[0], h4_, a0); a1 = dot4(s[1], h4_, a1); \
    a2 = dot4(s[2], h4_, a2); a3 = dot4(s[3], h4_, a3); }
#define LDSPH(jj2) { uint4 h4_ = hb[4 + (jj2)]; \
    uint4 w0_ = Wl[(size_t)((jj2) * 4 + 0) * 512 + tid]; \
    uint4 w1_ = Wl[(size_t)((jj2) * 4 + 1) * 512 + tid]; \
    uint4 w2_ = Wl[(size_t)((jj2) * 4 + 2) * 512 + tid]; \
    uint4 w3_ = Wl[(size_t)((jj2) * 4 + 3) * 512 + tid]; \
    a0 = dot4(w0_, h4_, a0); a1 = dot4(w1_, h4_, a1); \
    a2 = dot4(w2_, h4_, a2); a3 = dot4(w3_, h4_, a3); }

  for (int tl = 0; tl < Tc; tl++) {
    const int buf = tl & 1;
    const uint4* hb = hq + buf * 32 + half * 16;
    float a0 = 0, a1 = 0, a2 = 0, a3 = 0;
    uint4 sA[4], sB[4];
    LDB(sA, 0); LDB(sB, 1);
#pragma unroll
    for (int jj = 0; jj < 4; jj++) {   // opaque-VGPR phase (covers stream latency)
      uint4 h4 = hb[jj];
      a0 = dot4(wop[jj * 4 + 0], h4, a0);
      a1 = dot4(wop[jj * 4 + 1], h4, a1);
      a2 = dot4(wop[jj * 4 + 2], h4, a2);
      a3 = dot4(wop[jj * 4 + 3], h4, a3);
    }
    USEB(sA, 7);  LDB(sA, 2);
    LDSPH(0);
    USEB(sB, 8);  LDB(sB, 3);
    LDSPH(1);
    USEB(sA, 9);  LDB(sA, 4);
    LDSPH(2);
    USEB(sB, 10); LDB(sB, 5);
    USEB(sA, 11); LDB(sA, 6);
    USEB(sB, 12); LDB(sB, 7);
    USEB(sA, 13); LDB(sA, 8);
    USEB(sB, 14);
    USEB(sA, 15);

    if (half) pp[u] = make_float4(a0, a1, a2, a3);
    __syncthreads();
    if (!half) {
      float4 q = pp[u];
      float z0 = a0 + q.x + nx0, z1 = a1 + q.y + nx1;
      float z2 = a2 + q.z + nx2, z3 = a3 + q.w + nx3;
      if (tl + 1 < Tc) {
        const float* xn = xzb + (size_t)(tl + 1) * (Bsz * Zdim);
        nx0 = xn[0]; nx1 = xn[256]; nx2 = xn[512]; nx3 = xn[768];
      }
      float ig = sigm(z0), fg = sigm(z1), gg = tanh_f(z2), og = sigm(z3);
      c = fg * c + ig * gg;
      float hn = og * tanh_f(c);
      int ot = (t0 + tl) - (Tsz - n_out);
      if (ot >= 0) out[((size_t)b * n_out + ot) * UNITSn + u] = hn;
      ((__half*)(hq + (buf ^ 1) * 32))[u] = __float2half(hn);
    }
    __syncthreads();
  }
  if (tid < 32) h_state[(size_t)b * 32 + tid] = hq[(Tc & 1) * 32 + tid];
  if (half == 0) c_state[(size_t)b * 256 + u] = c;
#undef LDB
#undef USEB
#undef LDSPH
}

extern "C" void kernel_launch(void* const* d_in, const int* in_sizes, int n_in,
                              void* d_out, int out_size, void* d_ws, size_t ws_size,
                              hipStream_t stream) {
  const float* x    = (const float*)d_in[0];
  const float* U    = (const float*)d_in[1];
  const float* W    = (const float*)d_in[2];
  const float* bias = (const float*)d_in[3];
  float* out = (float*)d_out;
  const int n_out = out_size / (Bsz * UNITSn);   // 32

  uint8_t* ws = (uint8_t*)d_ws;
  uint4* Wop      = (uint4*)ws;                    // 128 KB (8192 uint4)
  uint4* Wlds     = (uint4*)(ws + (128u << 10));   //  96 KB (6144 uint4)
  uint4* Wstr     = (uint4*)(ws + (224u << 10));   // 288 KB (18432 uint4)
  _Float16* UT    = (_Float16*)(ws + (512u << 10));// 512 KB
  uint4* h_state  = (uint4*)(ws + (1024u << 10));  //  32 KB
  float* c_state  = (float*)(ws + (1056u << 10));  //  64 KB
  float* xz       = (float*)(ws + (2u << 20));     // Tc*64*1024 fp32

  int Tc = Tsz;
  while (Tc > 1 && (size_t)(2u << 20) + (size_t)Tc * (Bsz * Zdim) * 4 > ws_size) Tc >>= 1;

  convert_w5<<<dim3(128), dim3(256), 0, stream>>>(W, Wop, Wlds, Wstr);
  convert_u<<<dim3(1024), dim3(256), 0, stream>>>(U, UT);

  const int ldsBytes = (6144 + 64 + 256) * 16;     // 103424 B
  hipFuncSetAttribute((const void*)lstm_chunk,
                      hipFuncAttributeMaxDynamicSharedMemorySize, ldsBytes);

  for (int t0 = 0; t0 < Tsz; t0 += Tc) {
    proj_mfma<<<dim3(4, Tc), dim3(256), 0, stream>>>(x, UT, bias, xz, t0);
    lstm_chunk<<<dim3(Bsz), dim3(512), ldsBytes, stream>>>(xz, Wop, Wlds, Wstr,
                                                           out, h_state, c_state,
                                                           t0, Tc, n_out);
  }
}